// Round 5
// baseline (1307.967 us; speedup 1.0000x reference)
//
#include <hip/hip_runtime.h>
#include <math.h>

#define NPART 32
#define ADIM  20
#define ODIM  64
#define HID   256
#define NSTEPS 5
#define LRC   0.1f
#define NBLK  512     // 2 states per block
#define LOG33 3.4965075614664802f

typedef short bf8 __attribute__((ext_vector_type(8)));   // 8 bf16 (4 VGPRs)
typedef float f4  __attribute__((ext_vector_type(4)));   // MFMA C/D

// workspace layout (bf16 element offsets)
#define OW1T(n) ((n)*24576)             // [256 n][96 k]   w1^T, k-pad 84->96 (fwd L1 B)
#define OW2T(n) (49152 + (n)*65536)     // [256 n][256 k]  w2^T (fwd L2 B)
#define OW2C(n) (180224 + (n)*65536)    // raw w2 copy (bwd dh1 B)
#define OW1X(n) (311296 + (n)*8192)     // [32 d][256 n]   w1 act-rows, d>=20 zero (score B)
#define OW3B(n) (327680 + (n)*256)      // w3 bf16
#define WS_ELEMS 328192

__device__ __forceinline__ short f2bf(float x) {          // RNE f32->bf16 (prep only)
    unsigned u = __float_as_uint(x);
    u += 0x7FFFu + ((u >> 16) & 1u);
    return (short)(u >> 16);
}
__device__ __forceinline__ short f2bfT(float x) {         // truncating f32->bf16 (fast)
    return (short)(__float_as_uint(x) >> 16);
}
__device__ __forceinline__ float bf2f(short s) {
    return __uint_as_float(((unsigned)(unsigned short)s) << 16);
}

#define MFMA(a,b,c) __builtin_amdgcn_mfma_f32_16x16x32_bf16((a),(b),(c),0,0,0)

// ---------- prep: build bf16 weight images in ws ----------
__global__ void prep_weights(const float* __restrict__ w1a, const float* __restrict__ w2a,
                             const float* __restrict__ w3a, const float* __restrict__ w1b,
                             const float* __restrict__ w2b, const float* __restrict__ w3b,
                             unsigned short* __restrict__ ws)
{
    int idx = blockIdx.x * 256 + threadIdx.x;
    if (idx >= WS_ELEMS) return;
    float val;
    if (idx < 49152) {
        int net = idx / 24576, rem = idx % 24576;
        int n = rem / 96, k = rem % 96;
        const float* w1 = net ? w1b : w1a;
        val = (k < 84) ? w1[k*256 + n] : 0.f;
    } else if (idx < 180224) {
        int t2 = idx - 49152; int net = t2 / 65536, rem = t2 % 65536;
        int n = rem / 256, k = rem % 256;
        const float* w2 = net ? w2b : w2a;
        val = w2[k*256 + n];
    } else if (idx < 311296) {
        int t2 = idx - 180224; int net = t2 / 65536, rem = t2 % 65536;
        const float* w2 = net ? w2b : w2a;
        val = w2[rem];
    } else if (idx < 327680) {
        int t2 = idx - 311296; int net = t2 / 8192, rem = t2 % 8192;
        int d = rem / 256, n = rem % 256;
        const float* w1 = net ? w1b : w1a;
        val = (d < 20) ? w1[(64 + d)*256 + n] : 0.f;
    } else {
        int t2 = idx - 327680; int net = t2 / 256, k = t2 % 256;
        const float* w3 = net ? w3b : w3a;
        val = w3[k];
    }
    ws[idx] = (unsigned short)f2bf(val);
}

// ---------- main: 2 states per block, 512 threads, net-pipelined phases ----------
__global__ void __launch_bounds__(512, 4)
svgd_main(const float* __restrict__ obs,  const float* __restrict__ a0g,
          const float* __restrict__ b1a,  const float* __restrict__ b2a, const float* __restrict__ b3a,
          const float* __restrict__ b1b,  const float* __restrict__ b2b, const float* __restrict__ b3b,
          const float* __restrict__ w3af, const float* __restrict__ w3bf,
          const unsigned short* __restrict__ ws, float* __restrict__ out)
{
    __shared__ __align__(16) short A0s[64*96];      // [obs|X|pad] bf16, 2 states stacked
    __shared__ __align__(16) short hbuf[64*264];    // h1/g1 bf16; RBF shadows alias
    __shared__ unsigned maskS[2][2][64][8];         // relu bitmasks [net][layer][row][word]
    __shared__ float Xm[64*20];                     // fp32 master particles
    __shared__ float qpart[2][8][64];
    __shared__ int   winsS[64];
    __shared__ float logps[64];
    __shared__ unsigned short lutI[496], lutJ[496];
    __shared__ float med2[4];                        // [state][2]
    __shared__ float qvS[64];
    __shared__ float normsS[64], rowKS[64];

    // hbuf alias map (short offsets) — live only in the RBF tail of each step:
    float* d2sF = (float*)hbuf;          // shorts     0.. 4095 : d2s fp32 [2][32][32]
    float* GSF  = ((float*)hbuf) + 2048; // shorts  4096.. 8191 : X@S^T fp32 [2][32][32] (diag = x_i·s_i)
    short* KbS  = hbuf + 8192;           // shorts  8192..10239 : K bf16 [2][32][32]
    short* SBs  = hbuf + 10240;          // shorts 10240..12287 : S bf16 [64][32] (k-pad 0)
    short* STbS = hbuf + 12288;          // shorts 12288..14335 : S^T bf16 [2][32dd][32j]
    short* XTbS = hbuf + 14336;          // shorts 14336..16383 : X^T bf16 [2][32dd][32j]

    const int t = threadIdx.x, b = blockIdx.x;
    const int lane = t & 63, wv = t >> 6;           // 8 waves
    const int q = lane >> 4, mp = lane & 15;
    const int nb = wv * 32;                          // 32-col slice of the 256-wide GEMMs

    // ---- init ----
    for (int p = t; p < 64*ODIM; p += 512) {
        int i = p >> 6, d = p & 63;
        A0s[i*96 + d] = f2bfT(obs[(b*64 + i)*ODIM + d]);
    }
    for (int p = t; p < 64*ADIM; p += 512) {
        int i = p / 20, d = p - i*20;
        float v = a0g[(b*64 + i)*20 + d];
        Xm[p] = v;
        A0s[i*96 + 64 + d] = f2bfT(v);
    }
    for (int p = t; p < 64*12; p += 512) { int i = p/12, d = p - i*12; A0s[i*96 + 84 + d] = 0; }
    { unsigned* mz = &maskS[0][0][0][0];
      for (int p = t; p < 2*2*64*8; p += 512) mz[p] = 0u; }
    if (t < 496) {
        int i_ = 0, rem = t;
        while (rem >= 31 - i_) { rem -= 31 - i_; ++i_; }
        lutI[t] = (unsigned short)i_; lutJ[t] = (unsigned short)(i_ + 1 + rem);
    }
    if (t < 64) logps[t] = 0.f;
    __syncthreads();

    for (int step = 0; step < NSTEPS; ++step) {
        // =========== P_A: L1(net0) kloop + epi ===========
        {
            const unsigned short* w1t = ws + OW1T(0);
            f4 acc[4][2];
            #pragma unroll
            for (int h = 0; h < 4; ++h) { acc[h][0] = (f4){0,0,0,0}; acc[h][1] = (f4){0,0,0,0}; }
            #pragma unroll
            for (int k0 = 0; k0 < 96; k0 += 32) {
                bf8 bb0 = *(const bf8*)(w1t + (size_t)(nb +      mp)*96 + k0 + q*8);
                bf8 bb1 = *(const bf8*)(w1t + (size_t)(nb + 16 + mp)*96 + k0 + q*8);
                #pragma unroll
                for (int h = 0; h < 4; ++h) {
                    bf8 aa = *(const bf8*)&A0s[(h*16 + mp)*96 + k0 + q*8];
                    acc[h][0] = MFMA(aa, bb0, acc[h][0]);
                    acc[h][1] = MFMA(aa, bb1, acc[h][1]);
                }
            }
            // epi: h1(0) -> hbuf, mask0(0)   (no hbuf reads in this phase -> safe)
            #pragma unroll
            for (int h = 0; h < 4; ++h) {
                #pragma unroll
                for (int s = 0; s < 2; ++s) {
                    int n0 = nb + s*16, col = n0 + mp;
                    float bias = b1a[col];
                    #pragma unroll
                    for (int r = 0; r < 4; ++r) {
                        float v = acc[h][s][r] + bias;
                        bool pos = v > 0.f;
                        unsigned long long bal = __ballot(pos);
                        hbuf[(h*16 + q*4 + r)*264 + col] = f2bfT(pos ? v : 0.f);
                        if (mp == 0)
                            atomicOr(&maskS[0][0][h*16 + q*4 + r][n0 >> 5],
                                     ((unsigned)((bal >> (q*16)) & 0xFFFFull)) << (n0 & 16));
                    }
                }
            }
        }
        __syncthreads();   // B1

        // =========== P_B: L2(net0) kloop || L1(net1) kloop ===========
        f4 accL2[4][2], accL1[4][2];
        #pragma unroll
        for (int h = 0; h < 4; ++h) {
            accL2[h][0] = (f4){0,0,0,0}; accL2[h][1] = (f4){0,0,0,0};
            accL1[h][0] = (f4){0,0,0,0}; accL1[h][1] = (f4){0,0,0,0};
        }
        {
            const unsigned short* w2t = ws + OW2T(0);
            const unsigned short* w1t = ws + OW1T(1);
            #pragma unroll
            for (int k0 = 0; k0 < 256; k0 += 32) {
                bf8 b20 = *(const bf8*)(w2t + (size_t)(nb +      mp)*256 + k0 + q*8);
                bf8 b21 = *(const bf8*)(w2t + (size_t)(nb + 16 + mp)*256 + k0 + q*8);
                #pragma unroll
                for (int h = 0; h < 4; ++h) {
                    bf8 aa = *(const bf8*)&hbuf[(h*16 + mp)*264 + k0 + q*8];
                    accL2[h][0] = MFMA(aa, b20, accL2[h][0]);
                    accL2[h][1] = MFMA(aa, b21, accL2[h][1]);
                }
                if (k0 < 96) {
                    bf8 c0 = *(const bf8*)(w1t + (size_t)(nb +      mp)*96 + k0 + q*8);
                    bf8 c1 = *(const bf8*)(w1t + (size_t)(nb + 16 + mp)*96 + k0 + q*8);
                    #pragma unroll
                    for (int h = 0; h < 4; ++h) {
                        bf8 aa = *(const bf8*)&A0s[(h*16 + mp)*96 + k0 + q*8];
                        accL1[h][0] = MFMA(aa, c0, accL1[h][0]);
                        accL1[h][1] = MFMA(aa, c1, accL1[h][1]);
                    }
                }
            }
        }
        // L2(0) epi (no hbuf touch): qpart(0), mask1(0)
        {
            float qp[4][4] = {{0,0,0,0},{0,0,0,0},{0,0,0,0},{0,0,0,0}};
            #pragma unroll
            for (int h = 0; h < 4; ++h) {
                #pragma unroll
                for (int s = 0; s < 2; ++s) {
                    int n0 = nb + s*16, col = n0 + mp;
                    float bias = b2a[col], w3v = w3af[col];
                    #pragma unroll
                    for (int r = 0; r < 4; ++r) {
                        float v = accL2[h][s][r] + bias;
                        bool pos = v > 0.f;
                        unsigned long long bal = __ballot(pos);
                        if (mp == 0)
                            atomicOr(&maskS[0][1][h*16 + q*4 + r][n0 >> 5],
                                     ((unsigned)((bal >> (q*16)) & 0xFFFFull)) << (n0 & 16));
                        qp[h][r] += pos ? v * w3v : 0.f;
                    }
                }
            }
            #pragma unroll
            for (int d = 1; d < 16; d <<= 1)
                #pragma unroll
                for (int h = 0; h < 4; ++h)
                    #pragma unroll
                    for (int r = 0; r < 4; ++r)
                        qp[h][r] += __shfl_xor(qp[h][r], d, 64);
            if (mp == 0) {
                #pragma unroll
                for (int h = 0; h < 4; ++h)
                    #pragma unroll
                    for (int r = 0; r < 4; ++r)
                        qpart[0][wv][h*16 + q*4 + r] = qp[h][r];
            }
        }
        __syncthreads();   // B2: all L2(0) hbuf reads done
        // L1(1) epi: h1(1) -> hbuf (overwrites h1(0)), mask0(1)
        #pragma unroll
        for (int h = 0; h < 4; ++h) {
            #pragma unroll
            for (int s = 0; s < 2; ++s) {
                int n0 = nb + s*16, col = n0 + mp;
                float bias = b1b[col];
                #pragma unroll
                for (int r = 0; r < 4; ++r) {
                    float v = accL1[h][s][r] + bias;
                    bool pos = v > 0.f;
                    unsigned long long bal = __ballot(pos);
                    hbuf[(h*16 + q*4 + r)*264 + col] = f2bfT(pos ? v : 0.f);
                    if (mp == 0)
                        atomicOr(&maskS[1][0][h*16 + q*4 + r][n0 >> 5],
                                 ((unsigned)((bal >> (q*16)) & 0xFFFFull)) << (n0 & 16));
                }
            }
        }
        __syncthreads();   // B3

        // =========== P_C: L2(net1) kloop || bwd-dh1(net0) kloop ===========
        f4 accB0[4][2];
        #pragma unroll
        for (int h = 0; h < 4; ++h) {
            accL2[h][0] = (f4){0,0,0,0}; accL2[h][1] = (f4){0,0,0,0};
            accB0[h][0] = (f4){0,0,0,0}; accB0[h][1] = (f4){0,0,0,0};
        }
        {
            const unsigned short* w2t  = ws + OW2T(1);
            const unsigned short* w2c  = ws + OW2C(0);
            const unsigned short* w3b8 = ws + OW3B(0);
            #pragma unroll
            for (int k0 = 0; k0 < 256; k0 += 32) {
                bf8 b20 = *(const bf8*)(w2t + (size_t)(nb +      mp)*256 + k0 + q*8);
                bf8 b21 = *(const bf8*)(w2t + (size_t)(nb + 16 + mp)*256 + k0 + q*8);
                #pragma unroll
                for (int h = 0; h < 4; ++h) {
                    bf8 aa = *(const bf8*)&hbuf[(h*16 + mp)*264 + k0 + q*8];
                    accL2[h][0] = MFMA(aa, b20, accL2[h][0]);
                    accL2[h][1] = MFMA(aa, b21, accL2[h][1]);
                }
                bf8 c0 = *(const bf8*)(w2c + (size_t)(nb +      mp)*256 + k0 + q*8);
                bf8 c1 = *(const bf8*)(w2c + (size_t)(nb + 16 + mp)*256 + k0 + q*8);
                bf8 w3v = *(const bf8*)(w3b8 + k0 + q*8);
                #pragma unroll
                for (int h = 0; h < 4; ++h) {
                    unsigned bits = (maskS[0][1][h*16 + mp][k0 >> 5] >> (q*8)) & 0xFFu;
                    bf8 aa;
                    #pragma unroll
                    for (int j = 0; j < 8; ++j)
                        aa[j] = ((bits >> j) & 1u) ? w3v[j] : (short)0;
                    accB0[h][0] = MFMA(aa, c0, accB0[h][0]);
                    accB0[h][1] = MFMA(aa, c1, accB0[h][1]);
                }
            }
        }
        // L2(1) epi: qpart(1), mask1(1)  (no hbuf touch)
        {
            float qp[4][4] = {{0,0,0,0},{0,0,0,0},{0,0,0,0},{0,0,0,0}};
            #pragma unroll
            for (int h = 0; h < 4; ++h) {
                #pragma unroll
                for (int s = 0; s < 2; ++s) {
                    int n0 = nb + s*16, col = n0 + mp;
                    float bias = b2b[col], w3v = w3bf[col];
                    #pragma unroll
                    for (int r = 0; r < 4; ++r) {
                        float v = accL2[h][s][r] + bias;
                        bool pos = v > 0.f;
                        unsigned long long bal = __ballot(pos);
                        if (mp == 0)
                            atomicOr(&maskS[1][1][h*16 + q*4 + r][n0 >> 5],
                                     ((unsigned)((bal >> (q*16)) & 0xFFFFull)) << (n0 & 16));
                        qp[h][r] += pos ? v * w3v : 0.f;
                    }
                }
            }
            #pragma unroll
            for (int d = 1; d < 16; d <<= 1)
                #pragma unroll
                for (int h = 0; h < 4; ++h)
                    #pragma unroll
                    for (int r = 0; r < 4; ++r)
                        qp[h][r] += __shfl_xor(qp[h][r], d, 64);
            if (mp == 0) {
                #pragma unroll
                for (int h = 0; h < 4; ++h)
                    #pragma unroll
                    for (int r = 0; r < 4; ++r)
                        qpart[1][wv][h*16 + q*4 + r] = qp[h][r];
            }
        }
        __syncthreads();   // B5

        // =========== P_D: bwd-dh1(net1) kloop || argmin (wave 0) ===========
        if (t < 64) {
            float q0 = b3a[0], q1 = b3b[0];
            #pragma unroll
            for (int w = 0; w < 8; ++w) { q0 += qpart[0][w][t]; q1 += qpart[1][w][t]; }
            winsS[t] = (q0 <= q1) ? 0 : 1;
        }
        f4 accB1[4][2];
        #pragma unroll
        for (int h = 0; h < 4; ++h) { accB1[h][0] = (f4){0,0,0,0}; accB1[h][1] = (f4){0,0,0,0}; }
        {
            const unsigned short* w2c  = ws + OW2C(1);
            const unsigned short* w3b8 = ws + OW3B(1);
            #pragma unroll
            for (int k0 = 0; k0 < 256; k0 += 32) {
                bf8 c0 = *(const bf8*)(w2c + (size_t)(nb +      mp)*256 + k0 + q*8);
                bf8 c1 = *(const bf8*)(w2c + (size_t)(nb + 16 + mp)*256 + k0 + q*8);
                bf8 w3v = *(const bf8*)(w3b8 + k0 + q*8);
                #pragma unroll
                for (int h = 0; h < 4; ++h) {
                    unsigned bits = (maskS[1][1][h*16 + mp][k0 >> 5] >> (q*8)) & 0xFFu;
                    bf8 aa;
                    #pragma unroll
                    for (int j = 0; j < 8; ++j)
                        aa[j] = ((bits >> j) & 1u) ? w3v[j] : (short)0;
                    accB1[h][0] = MFMA(aa, c0, accB1[h][0]);
                    accB1[h][1] = MFMA(aa, c1, accB1[h][1]);
                }
            }
        }
        __syncthreads();   // B6 (winsS ready; hbuf reads of P_C long done)
        // g1(0) -> hbuf, gated by win(row) && mask0(0)
        #pragma unroll
        for (int h = 0; h < 4; ++h) {
            #pragma unroll
            for (int s = 0; s < 2; ++s) {
                int col = nb + s*16 + mp;
                #pragma unroll
                for (int r = 0; r < 4; ++r) {
                    int row = h*16 + q*4 + r;
                    bool on = (winsS[row] == 0) &&
                              ((maskS[0][0][row][col >> 5] >> (col & 31)) & 1u);
                    hbuf[row*264 + col] = f2bfT(on ? accB0[h][s][r] : 0.f);
                }
            }
        }
        __syncthreads();   // B7

        // =========== P_E: score(net0) kloop ===========
        const int mt = wv & 3, ch = wv >> 2;
        f4 sa0 = (f4){0,0,0,0};
        {
            const unsigned short* w1x = ws + OW1X(0);
            #pragma unroll
            for (int k0 = 0; k0 < 256; k0 += 32) {
                bf8 bx = *(const bf8*)(w1x + (size_t)(ch*16 + mp)*256 + k0 + q*8);
                bf8 aa = *(const bf8*)&hbuf[(mt*16 + mp)*264 + k0 + q*8];
                sa0 = MFMA(aa, bx, sa0);
            }
        }
        __syncthreads();   // B8
        // g1(1) -> hbuf
        #pragma unroll
        for (int h = 0; h < 4; ++h) {
            #pragma unroll
            for (int s = 0; s < 2; ++s) {
                int col = nb + s*16 + mp;
                #pragma unroll
                for (int r = 0; r < 4; ++r) {
                    int row = h*16 + q*4 + r;
                    bool on = (winsS[row] == 1) &&
                              ((maskS[1][0][row][col >> 5] >> (col & 31)) & 1u);
                    hbuf[row*264 + col] = f2bfT(on ? accB1[h][s][r] : 0.f);
                }
            }
        }
        __syncthreads();   // B9

        // =========== P_F: score(net1) kloop ===========
        f4 sa = sa0;
        {
            const unsigned short* w1x = ws + OW1X(1);
            #pragma unroll
            for (int k0 = 0; k0 < 256; k0 += 32) {
                bf8 bx = *(const bf8*)(w1x + (size_t)(ch*16 + mp)*256 + k0 + q*8);
                bf8 aa = *(const bf8*)&hbuf[(mt*16 + mp)*264 + k0 + q*8];
                sa = MFMA(aa, bx, sa);
            }
        }
        __syncthreads();   // B10 (all g1 reads done; alias region free)

        // score epi: S shadows (bf16) from regs; X^T shadow + norms by t<64
        {
            int colD = ch*16 + mp;               // 0..31 (cols >=20 are exact zeros)
            #pragma unroll
            for (int r = 0; r < 4; ++r) {
                int row = mt*16 + q*4 + r, st = row >> 5, il = row & 31;
                short sb = f2bfT(sa[r]);
                SBs[row*32 + colD] = sb;
                STbS[st*1024 + colD*32 + il] = sb;
            }
        }
        if (t < 64) {
            int st = t >> 5, il = t & 31;
            float nrm = 0.f;
            #pragma unroll
            for (int d = 0; d < 20; ++d) {
                float xb = bf2f(A0s[t*96 + 64 + d]);
                nrm += xb * xb;
                XTbS[st*1024 + d*32 + il] = f2bfT(Xm[t*20 + d]);
            }
            #pragma unroll
            for (int d = 20; d < 32; ++d) XTbS[st*1024 + d*32 + il] = 0;
            normsS[t] = nrm;
        }
        __syncthreads();   // B11

        // =========== P_G: d2s = n_i+n_j-2*XX^T ; GS = X S^T (diag = x_i·s_i) ===========
        {
            int stw = wv >> 2, mtl = (wv >> 1) & 1, ntl = wv & 1;
            bf8 aa  = *(const bf8*)&A0s[(stw*32 + mtl*16 + mp)*96 + 64 + q*8];
            bf8 bbx = *(const bf8*)&A0s[(stw*32 + ntl*16 + mp)*96 + 64 + q*8];
            bf8 bbs = *(const bf8*)&SBs[(stw*32 + ntl*16 + mp)*32 + q*8];
            f4 gx = MFMA(aa, bbx, ((f4){0,0,0,0}));
            f4 gs = MFMA(aa, bbs, ((f4){0,0,0,0}));
            int jl = ntl*16 + mp;
            float nj = normsS[stw*32 + jl];
            #pragma unroll
            for (int r = 0; r < 4; ++r) {
                int il = mtl*16 + q*4 + r;
                d2sF[stw*1024 + il*32 + jl] = normsS[stw*32 + il] + nj - 2.f*gx[r];
                GSF [stw*1024 + il*32 + jl] = gs[r];
            }
        }
        __syncthreads();   // B12

        // =========== P_H: waves 0-1 median sort; waves 2-7 zero masks ===========
        if (wv < 2) {
            const float* base = d2sF + wv*1024;
            float v[8];
            #pragma unroll
            for (int i = 0; i < 8; ++i) {
                int e = lane*8 + i;
                v[i] = (e < 496) ? base[lutI[e]*32 + lutJ[e]] : 3.4e38f;
            }
            for (int k = 2; k <= 512; k <<= 1) {
                for (int jj = k >> 1; jj >= 8; jj >>= 1) {
                    int lm = jj >> 3;
                    #pragma unroll
                    for (int i = 0; i < 8; ++i) {
                        float w = __shfl_xor(v[i], lm, 64);
                        int p = lane*8 + i;
                        bool takeMin = (((p & k) == 0) == ((p & jj) == 0));
                        v[i] = takeMin ? fminf(v[i], w) : fmaxf(v[i], w);
                    }
                }
                int jj0 = (k >> 1) < 4 ? (k >> 1) : 4;
                for (int jj = jj0; jj >= 1; jj >>= 1) {
                    #pragma unroll
                    for (int i = 0; i < 8; ++i) {
                        if ((i & jj) == 0) {
                            int i2 = i | jj;
                            int p = lane*8 + i;
                            bool up = ((p & k) == 0);
                            float x = v[i], y = v[i2];
                            float mn = fminf(x, y), mx = fmaxf(x, y);
                            v[i] = up ? mn : mx; v[i2] = up ? mx : mn;
                        }
                    }
                }
            }
            if (lane == 29) med2[wv*2 + 0] = v[7];   // sorted index 239
            if (lane == 30) med2[wv*2 + 1] = v[0];   // sorted index 240
        } else {
            unsigned* mz = &maskS[0][0][0][0];
            for (int p = t - 128; p < 2*2*64*8; p += 384) mz[p] = 0u;
        }
        __syncthreads();   // B13

        // =========== P_I: K = exp(-g d2), logp row-terms, rowK ===========
        {
            int i = t >> 3, stw = i >> 5, il = i & 31, j0 = (t & 7) * 4;
            float medv = 0.5f * (med2[stw*2] + med2[stw*2 + 1]);
            float gam  = 1.f / (2.f * (medv / (2.f * LOG33)) + 1e-8f);
            float sK = 0.f, sKGS = 0.f, sKd2 = 0.f, sKdg = 0.f;
            #pragma unroll
            for (int jj = 0; jj < 4; ++jj) {
                int j = j0 + jj;
                float d2 = d2sF[stw*1024 + il*32 + j];
                float K  = expf(-gam * d2);
                KbS[stw*1024 + il*32 + j] = f2bfT(K);
                sK   += K;
                sKGS += K * GSF[stw*1024 + il*32 + j];
                sKd2 += K * d2;
                sKdg += K * GSF[stw*1024 + j*32 + j];   // diag GS_jj = x_j·s_j
            }
            #pragma unroll
            for (int d = 1; d < 8; d <<= 1) {
                sK   += __shfl_xor(sK,   d, 64);
                sKGS += __shfl_xor(sKGS, d, 64);
                sKd2 += __shfl_xor(sKd2, d, 64);
                sKdg += __shfl_xor(sKdg, d, 64);
            }
            if ((t & 7) == 0) {
                rowKS[i] = sK;
                float sdots = sKGS - sKdg;
                float ssum  = -2.f*gam*sdots
                              - 2.f*gam*(2.f*gam*sKd2 - 20.f*(sK - 1.f));
                logps[i] -= LRC * (ssum * (1.f/32.f));
            }
        }
        __syncthreads();   // B14

        // =========== P_J: phi = (K@S + 2g(x*rowK - K@X))/32 ; X += LR*phi ===========
        {
            int stw = wv >> 2, mtl = (wv >> 1) & 1, ntl = wv & 1;
            float medv = 0.5f * (med2[stw*2] + med2[stw*2 + 1]);
            float gam  = 1.f / (2.f * (medv / (2.f * LOG33)) + 1e-8f);
            bf8 aa  = *(const bf8*)&KbS [stw*1024 + (mtl*16 + mp)*32 + q*8];
            bf8 b1v = *(const bf8*)&STbS[stw*1024 + (ntl*16 + mp)*32 + q*8];
            bf8 b2v = *(const bf8*)&XTbS[stw*1024 + (ntl*16 + mp)*32 + q*8];
            f4 ks = MFMA(aa, b1v, ((f4){0,0,0,0}));
            f4 kx = MFMA(aa, b2v, ((f4){0,0,0,0}));
            int dd = ntl*16 + mp;
            if (dd < 20) {
                #pragma unroll
                for (int r = 0; r < 4; ++r) {
                    int gi = stw*32 + mtl*16 + q*4 + r;
                    float xi  = Xm[gi*20 + dd];
                    float phi = (ks[r] + 2.f*gam*(xi*rowKS[gi] - kx[r])) * (1.f/32.f);
                    float nx  = xi + LRC * phi;
                    Xm[gi*20 + dd] = nx;
                    A0s[gi*96 + 64 + dd] = f2bfT(nx);
                }
            }
        }
        __syncthreads();   // B15
    } // steps

    // ================= epilogue =================
    for (int p = t; p < 64*20; p += 512) {
        int i = p / 20, d = p - i*20;
        out[(b*64 + i)*20 + d] = tanhf(Xm[p]);
    }
    if (t < 64) {
        float lt = 0.f, s0 = 0.f;
        for (int d = 0; d < 20; ++d) {
            float a  = Xm[t*20 + d];
            float x  = -2.f * a;
            float sp = fmaxf(x, 0.f) + log1pf(expf(-fabsf(x)));
            lt -= 2.f * (0.69314718056f - a - sp);
            float v = a0g[(b*64 + t)*20 + d];
            s0 += v * v;
        }
        qvS[t] = -18.3787706641f - 0.5f*s0 + logps[t] + lt;
    }
    __syncthreads();
    if (t < 2) {
        float s = 0.f;
        for (int i = 0; i < 32; ++i) s += qvS[t*32 + i];
        out[1024*32*20 + b*2 + t] = s * (1.f/32.f);
    }
}

extern "C" void kernel_launch(void* const* d_in, const int* in_sizes, int n_in,
                              void* d_out, int out_size, void* d_ws, size_t ws_size,
                              hipStream_t stream) {
    unsigned short* ws = (unsigned short*)d_ws;
    prep_weights<<<(WS_ELEMS + 255)/256, 256, 0, stream>>>(
        (const float*)d_in[2],  (const float*)d_in[4],  (const float*)d_in[6],
        (const float*)d_in[8],  (const float*)d_in[10], (const float*)d_in[12], ws);
    svgd_main<<<NBLK, 512, 0, stream>>>(
        (const float*)d_in[0],  (const float*)d_in[1],
        (const float*)d_in[3],  (const float*)d_in[5],  (const float*)d_in[7],
        (const float*)d_in[9],  (const float*)d_in[11], (const float*)d_in[13],
        (const float*)d_in[6],  (const float*)d_in[12],
        ws, (float*)d_out);
}

// Round 6
// 829.239 us; speedup vs baseline: 1.5773x; 1.5773x over previous
//
#include <hip/hip_runtime.h>
#include <math.h>

#define NPART 32
#define ADIM  20
#define ODIM  64
#define HID   256
#define NSTEPS 5
#define LRC   0.1f
#define NBLK  512     // 2 states per block
#define LOG33 3.4965075614664802f

typedef short bf8 __attribute__((ext_vector_type(8)));   // 8 bf16 (4 VGPRs)
typedef float f4  __attribute__((ext_vector_type(4)));   // MFMA C/D

// workspace layout (bf16 element offsets)
#define OW1T(n) ((n)*24576)             // [256 n][96 k]   w1^T, k-pad 84->96 (fwd L1 B)
#define OW2T(n) (49152 + (n)*65536)     // [256 n][256 k]  w2^T (fwd L2 B)
#define OW2C(n) (180224 + (n)*65536)    // raw w2 copy (bwd dh1 B)
#define OW1X(n) (311296 + (n)*8192)     // [32 d][256 n]   w1 act-rows, d>=20 zero (score B)
#define OW3B(n) (327680 + (n)*256)      // w3 bf16
#define WS_ELEMS 328192

__device__ __forceinline__ short f2bf(float x) {          // RNE f32->bf16 (prep only)
    unsigned u = __float_as_uint(x);
    u += 0x7FFFu + ((u >> 16) & 1u);
    return (short)(u >> 16);
}
__device__ __forceinline__ short f2bfT(float x) {         // truncating f32->bf16 (fast)
    return (short)(__float_as_uint(x) >> 16);
}
__device__ __forceinline__ float bf2f(short s) {
    return __uint_as_float(((unsigned)(unsigned short)s) << 16);
}

#define MFMA(a,b,c) __builtin_amdgcn_mfma_f32_16x16x32_bf16((a),(b),(c),0,0,0)

// ---------- prep: build bf16 weight images in ws ----------
__global__ void prep_weights(const float* __restrict__ w1a, const float* __restrict__ w2a,
                             const float* __restrict__ w3a, const float* __restrict__ w1b,
                             const float* __restrict__ w2b, const float* __restrict__ w3b,
                             unsigned short* __restrict__ ws)
{
    int idx = blockIdx.x * 256 + threadIdx.x;
    if (idx >= WS_ELEMS) return;
    float val;
    if (idx < 49152) {
        int net = idx / 24576, rem = idx % 24576;
        int n = rem / 96, k = rem % 96;
        const float* w1 = net ? w1b : w1a;
        val = (k < 84) ? w1[k*256 + n] : 0.f;
    } else if (idx < 180224) {
        int t2 = idx - 49152; int net = t2 / 65536, rem = t2 % 65536;
        int n = rem / 256, k = rem % 256;
        const float* w2 = net ? w2b : w2a;
        val = w2[k*256 + n];
    } else if (idx < 311296) {
        int t2 = idx - 180224; int net = t2 / 65536, rem = t2 % 65536;
        const float* w2 = net ? w2b : w2a;
        val = w2[rem];
    } else if (idx < 327680) {
        int t2 = idx - 311296; int net = t2 / 8192, rem = t2 % 8192;
        int d = rem / 256, n = rem % 256;
        const float* w1 = net ? w1b : w1a;
        val = (d < 20) ? w1[(64 + d)*256 + n] : 0.f;
    } else {
        int t2 = idx - 327680; int net = t2 / 256, k = t2 % 256;
        const float* w3 = net ? w3b : w3a;
        val = w3[k];
    }
    ws[idx] = (unsigned short)f2bf(val);
}

// ---------- main: 2 states per block, 512 threads, mask-free serial phases ----------
__global__ void __launch_bounds__(512, 4)
svgd_main(const float* __restrict__ obs,  const float* __restrict__ a0g,
          const float* __restrict__ b1a,  const float* __restrict__ b2a, const float* __restrict__ b3a,
          const float* __restrict__ b1b,  const float* __restrict__ b2b, const float* __restrict__ b3b,
          const float* __restrict__ w3af, const float* __restrict__ w3bf,
          const unsigned short* __restrict__ ws, float* __restrict__ out)
{
    __shared__ __align__(16) short A0s[64*96];      // [obs|X|pad] bf16, 2 states stacked
    __shared__ __align__(16) short hbuf[64*264];    // h1 -> g2 -> g1 bf16; RBF arrays alias
    __shared__ float Xm[64*20];                     // fp32 master particles
    __shared__ float qpart[2][8][64];
    __shared__ int   winsS[64];
    __shared__ float logps[64];
    __shared__ unsigned short lutI[496], lutJ[496];
    __shared__ float med2[4];                        // [state][2]
    __shared__ float qvS[64];
    __shared__ float normsS[64], rowKS[64];

    // hbuf alias map (short offsets) — live only in the RBF tail of each step:
    float* d2sF = (float*)hbuf;          // shorts     0.. 4095 : d2s fp32 [2][32][32]
    float* GSF  = ((float*)hbuf) + 2048; // shorts  4096.. 8191 : X@S^T fp32 (diag = x_i·s_i)
    short* KbS  = hbuf + 8192;           // shorts  8192..10239 : K bf16 [2][32][32]
    short* SBs  = hbuf + 10240;          // shorts 10240..12287 : S bf16 [64][32] (k-pad 0)
    short* STbS = hbuf + 12288;          // shorts 12288..14335 : S^T bf16 [2][32dd][32j]
    short* XTbS = hbuf + 14336;          // shorts 14336..16383 : X^T bf16 [2][32dd][32j]

    const int t = threadIdx.x, b = blockIdx.x;
    const int lane = t & 63, wv = t >> 6;           // 8 waves
    const int q = lane >> 4, mp = lane & 15;
    const int nb = wv * 32;                          // 32-col slice of the 256-wide GEMMs

    // ---- init ----
    for (int p = t; p < 64*ODIM; p += 512) {
        int i = p >> 6, d = p & 63;
        A0s[i*96 + d] = f2bfT(obs[(b*64 + i)*ODIM + d]);
    }
    for (int p = t; p < 64*ADIM; p += 512) {
        int i = p / 20, d = p - i*20;
        float v = a0g[(b*64 + i)*20 + d];
        Xm[p] = v;
        A0s[i*96 + 64 + d] = f2bfT(v);
    }
    for (int p = t; p < 64*12; p += 512) { int i = p/12, d = p - i*12; A0s[i*96 + 84 + d] = 0; }
    if (t < 496) {
        int i_ = 0, rem = t;
        while (rem >= 31 - i_) { rem -= 31 - i_; ++i_; }
        lutI[t] = (unsigned short)i_; lutJ[t] = (unsigned short)(i_ + 1 + rem);
    }
    if (t < 64) logps[t] = 0.f;
    __syncthreads();

    for (int step = 0; step < NSTEPS; ++step) {
        unsigned m0reg0, m0reg1;          // per-thread relu-L1 bits, bit = h*8+s*4+r
        f4 accB0[4][2], accB1[4][2];      // dh1 accumulators, live until g1 write

        // ======== P1: L1(net0) kloop + epi ========
        {
            const unsigned short* w1t = ws + OW1T(0);
            f4 acc[4][2];
            #pragma unroll
            for (int h = 0; h < 4; ++h) { acc[h][0] = (f4){0,0,0,0}; acc[h][1] = (f4){0,0,0,0}; }
            #pragma unroll
            for (int k0 = 0; k0 < 96; k0 += 32) {
                bf8 bb0 = *(const bf8*)(w1t + (size_t)(nb +      mp)*96 + k0 + q*8);
                bf8 bb1 = *(const bf8*)(w1t + (size_t)(nb + 16 + mp)*96 + k0 + q*8);
                #pragma unroll
                for (int h = 0; h < 4; ++h) {
                    bf8 aa = *(const bf8*)&A0s[(h*16 + mp)*96 + k0 + q*8];
                    acc[h][0] = MFMA(aa, bb0, acc[h][0]);
                    acc[h][1] = MFMA(aa, bb1, acc[h][1]);
                }
            }
            unsigned mbits = 0u;
            #pragma unroll
            for (int h = 0; h < 4; ++h) {
                #pragma unroll
                for (int s = 0; s < 2; ++s) {
                    int col = nb + s*16 + mp;
                    float bias = b1a[col];
                    #pragma unroll
                    for (int r = 0; r < 4; ++r) {
                        float v = acc[h][s][r] + bias;
                        bool pos = v > 0.f;
                        if (pos) mbits |= 1u << (h*8 + s*4 + r);
                        hbuf[(h*16 + q*4 + r)*264 + col] = f2bfT(pos ? v : 0.f);
                    }
                }
            }
            m0reg0 = mbits;
        }
        __syncthreads();   // B1: h1(0) ready

        // ======== P2: L2(net0) kloop; epi: qpart(0); then g2(0) -> hbuf ========
        {
            const unsigned short* w2t = ws + OW2T(0);
            f4 acc[4][2];
            #pragma unroll
            for (int h = 0; h < 4; ++h) { acc[h][0] = (f4){0,0,0,0}; acc[h][1] = (f4){0,0,0,0}; }
            #pragma unroll
            for (int k0 = 0; k0 < 256; k0 += 32) {
                bf8 bb0 = *(const bf8*)(w2t + (size_t)(nb +      mp)*256 + k0 + q*8);
                bf8 bb1 = *(const bf8*)(w2t + (size_t)(nb + 16 + mp)*256 + k0 + q*8);
                #pragma unroll
                for (int h = 0; h < 4; ++h) {
                    bf8 aa = *(const bf8*)&hbuf[(h*16 + mp)*264 + k0 + q*8];
                    acc[h][0] = MFMA(aa, bb0, acc[h][0]);
                    acc[h][1] = MFMA(aa, bb1, acc[h][1]);
                }
            }
            // epi: q partials + pos bits (no hbuf writes yet)
            unsigned posreg = 0u;
            {
                float qp[4][4] = {{0,0,0,0},{0,0,0,0},{0,0,0,0},{0,0,0,0}};
                #pragma unroll
                for (int h = 0; h < 4; ++h) {
                    #pragma unroll
                    for (int s = 0; s < 2; ++s) {
                        int col = nb + s*16 + mp;
                        float bias = b2a[col], w3v = w3af[col];
                        #pragma unroll
                        for (int r = 0; r < 4; ++r) {
                            float v = acc[h][s][r] + bias;
                            bool pos = v > 0.f;
                            if (pos) posreg |= 1u << (h*8 + s*4 + r);
                            qp[h][r] += pos ? v * w3v : 0.f;
                        }
                    }
                }
                #pragma unroll
                for (int d = 1; d < 16; d <<= 1)
                    #pragma unroll
                    for (int h = 0; h < 4; ++h)
                        #pragma unroll
                        for (int r = 0; r < 4; ++r)
                            qp[h][r] += __shfl_xor(qp[h][r], d, 64);
                if (mp == 0) {
                    #pragma unroll
                    for (int h = 0; h < 4; ++h)
                        #pragma unroll
                        for (int r = 0; r < 4; ++r)
                            qpart[0][wv][h*16 + q*4 + r] = qp[h][r];
                }
            }
            __syncthreads();   // B2: all h1(0) reads done
            // g2(0) = relu'(z2)*w3 bf16 -> hbuf
            short w3s0 = (short)ws[OW3B(0) + nb + mp];
            short w3s1 = (short)ws[OW3B(0) + nb + 16 + mp];
            #pragma unroll
            for (int h = 0; h < 4; ++h) {
                #pragma unroll
                for (int s = 0; s < 2; ++s) {
                    int col = nb + s*16 + mp;
                    short wv3 = s ? w3s1 : w3s0;
                    #pragma unroll
                    for (int r = 0; r < 4; ++r) {
                        bool on = (posreg >> (h*8 + s*4 + r)) & 1u;
                        hbuf[(h*16 + q*4 + r)*264 + col] = on ? wv3 : (short)0;
                    }
                }
            }
        }
        __syncthreads();   // B3: g2(0) ready

        // ======== P3: bwd-dh1(net0) kloop (std GEMM) || L1(net1) kloop ========
        {
            f4 accL1[4][2];
            #pragma unroll
            for (int h = 0; h < 4; ++h) {
                accB0[h][0] = (f4){0,0,0,0}; accB0[h][1] = (f4){0,0,0,0};
                accL1[h][0] = (f4){0,0,0,0}; accL1[h][1] = (f4){0,0,0,0};
            }
            const unsigned short* w2c = ws + OW2C(0);
            const unsigned short* w1t = ws + OW1T(1);
            #pragma unroll
            for (int k0 = 0; k0 < 256; k0 += 32) {
                bf8 c0 = *(const bf8*)(w2c + (size_t)(nb +      mp)*256 + k0 + q*8);
                bf8 c1 = *(const bf8*)(w2c + (size_t)(nb + 16 + mp)*256 + k0 + q*8);
                #pragma unroll
                for (int h = 0; h < 4; ++h) {
                    bf8 aa = *(const bf8*)&hbuf[(h*16 + mp)*264 + k0 + q*8];
                    accB0[h][0] = MFMA(aa, c0, accB0[h][0]);
                    accB0[h][1] = MFMA(aa, c1, accB0[h][1]);
                }
                if (k0 < 96) {
                    bf8 d0 = *(const bf8*)(w1t + (size_t)(nb +      mp)*96 + k0 + q*8);
                    bf8 d1 = *(const bf8*)(w1t + (size_t)(nb + 16 + mp)*96 + k0 + q*8);
                    #pragma unroll
                    for (int h = 0; h < 4; ++h) {
                        bf8 aa = *(const bf8*)&A0s[(h*16 + mp)*96 + k0 + q*8];
                        accL1[h][0] = MFMA(aa, d0, accL1[h][0]);
                        accL1[h][1] = MFMA(aa, d1, accL1[h][1]);
                    }
                }
            }
            __syncthreads();   // B4: g2(0) reads done
            // L1(1) epi: h1(1) -> hbuf
            unsigned mbits = 0u;
            #pragma unroll
            for (int h = 0; h < 4; ++h) {
                #pragma unroll
                for (int s = 0; s < 2; ++s) {
                    int col = nb + s*16 + mp;
                    float bias = b1b[col];
                    #pragma unroll
                    for (int r = 0; r < 4; ++r) {
                        float v = accL1[h][s][r] + bias;
                        bool pos = v > 0.f;
                        if (pos) mbits |= 1u << (h*8 + s*4 + r);
                        hbuf[(h*16 + q*4 + r)*264 + col] = f2bfT(pos ? v : 0.f);
                    }
                }
            }
            m0reg1 = mbits;
        }
        __syncthreads();   // B5: h1(1) ready

        // ======== P4: L2(net1) kloop; epi qpart(1); g2(1) -> hbuf; argmin ========
        {
            const unsigned short* w2t = ws + OW2T(1);
            f4 acc[4][2];
            #pragma unroll
            for (int h = 0; h < 4; ++h) { acc[h][0] = (f4){0,0,0,0}; acc[h][1] = (f4){0,0,0,0}; }
            #pragma unroll
            for (int k0 = 0; k0 < 256; k0 += 32) {
                bf8 bb0 = *(const bf8*)(w2t + (size_t)(nb +      mp)*256 + k0 + q*8);
                bf8 bb1 = *(const bf8*)(w2t + (size_t)(nb + 16 + mp)*256 + k0 + q*8);
                #pragma unroll
                for (int h = 0; h < 4; ++h) {
                    bf8 aa = *(const bf8*)&hbuf[(h*16 + mp)*264 + k0 + q*8];
                    acc[h][0] = MFMA(aa, bb0, acc[h][0]);
                    acc[h][1] = MFMA(aa, bb1, acc[h][1]);
                }
            }
            unsigned posreg = 0u;
            {
                float qp[4][4] = {{0,0,0,0},{0,0,0,0},{0,0,0,0},{0,0,0,0}};
                #pragma unroll
                for (int h = 0; h < 4; ++h) {
                    #pragma unroll
                    for (int s = 0; s < 2; ++s) {
                        int col = nb + s*16 + mp;
                        float bias = b2b[col], w3v = w3bf[col];
                        #pragma unroll
                        for (int r = 0; r < 4; ++r) {
                            float v = acc[h][s][r] + bias;
                            bool pos = v > 0.f;
                            if (pos) posreg |= 1u << (h*8 + s*4 + r);
                            qp[h][r] += pos ? v * w3v : 0.f;
                        }
                    }
                }
                #pragma unroll
                for (int d = 1; d < 16; d <<= 1)
                    #pragma unroll
                    for (int h = 0; h < 4; ++h)
                        #pragma unroll
                        for (int r = 0; r < 4; ++r)
                            qp[h][r] += __shfl_xor(qp[h][r], d, 64);
                if (mp == 0) {
                    #pragma unroll
                    for (int h = 0; h < 4; ++h)
                        #pragma unroll
                        for (int r = 0; r < 4; ++r)
                            qpart[1][wv][h*16 + q*4 + r] = qp[h][r];
                }
            }
            __syncthreads();   // B6: h1(1) reads + qpart(1) done
            short w3s0 = (short)ws[OW3B(1) + nb + mp];
            short w3s1 = (short)ws[OW3B(1) + nb + 16 + mp];
            #pragma unroll
            for (int h = 0; h < 4; ++h) {
                #pragma unroll
                for (int s = 0; s < 2; ++s) {
                    int col = nb + s*16 + mp;
                    short wv3 = s ? w3s1 : w3s0;
                    #pragma unroll
                    for (int r = 0; r < 4; ++r) {
                        bool on = (posreg >> (h*8 + s*4 + r)) & 1u;
                        hbuf[(h*16 + q*4 + r)*264 + col] = on ? wv3 : (short)0;
                    }
                }
            }
            if (t < 64) {   // argmin
                float q0 = b3a[0], q1 = b3b[0];
                #pragma unroll
                for (int w = 0; w < 8; ++w) { q0 += qpart[0][w][t]; q1 += qpart[1][w][t]; }
                winsS[t] = (q0 <= q1) ? 0 : 1;
            }
        }
        __syncthreads();   // B7: g2(1) + winsS ready

        // ======== P5: bwd-dh1(net1) kloop (std GEMM) ========
        {
            #pragma unroll
            for (int h = 0; h < 4; ++h) { accB1[h][0] = (f4){0,0,0,0}; accB1[h][1] = (f4){0,0,0,0}; }
            const unsigned short* w2c = ws + OW2C(1);
            #pragma unroll
            for (int k0 = 0; k0 < 256; k0 += 32) {
                bf8 c0 = *(const bf8*)(w2c + (size_t)(nb +      mp)*256 + k0 + q*8);
                bf8 c1 = *(const bf8*)(w2c + (size_t)(nb + 16 + mp)*256 + k0 + q*8);
                #pragma unroll
                for (int h = 0; h < 4; ++h) {
                    bf8 aa = *(const bf8*)&hbuf[(h*16 + mp)*264 + k0 + q*8];
                    accB1[h][0] = MFMA(aa, c0, accB1[h][0]);
                    accB1[h][1] = MFMA(aa, c1, accB1[h][1]);
                }
            }
        }
        __syncthreads();   // B8: g2(1) reads done

        // ======== combined g1 write: row takes winning net's dh1 * mask0 ========
        #pragma unroll
        for (int h = 0; h < 4; ++h) {
            #pragma unroll
            for (int s = 0; s < 2; ++s) {
                int col = nb + s*16 + mp;
                #pragma unroll
                for (int r = 0; r < 4; ++r) {
                    int row = h*16 + q*4 + r;
                    int w = winsS[row];
                    float dv   = w ? accB1[h][s][r] : accB0[h][s][r];
                    unsigned mr = w ? m0reg1 : m0reg0;
                    bool on = (mr >> (h*8 + s*4 + r)) & 1u;
                    hbuf[row*264 + col] = f2bfT(on ? dv : 0.f);
                }
            }
        }
        __syncthreads();   // B9: g1 ready

        // ======== P6: score = g1(gated rows) @ w1x(0) + g1(gated) @ w1x(1) ========
        const int mt = wv & 3, ch = wv >> 2;
        f4 sa = (f4){0,0,0,0};
        {
            const unsigned short* w1x0 = ws + OW1X(0);
            const unsigned short* w1x1 = ws + OW1X(1);
            short g0m = (winsS[mt*16 + mp] == 0) ? (short)-1 : (short)0;
            short g1m = (short)~g0m;
            bf8 mv0 = (bf8){g0m,g0m,g0m,g0m,g0m,g0m,g0m,g0m};
            bf8 mv1 = (bf8){g1m,g1m,g1m,g1m,g1m,g1m,g1m,g1m};
            #pragma unroll
            for (int k0 = 0; k0 < 256; k0 += 32) {
                bf8 bx0 = *(const bf8*)(w1x0 + (size_t)(ch*16 + mp)*256 + k0 + q*8);
                bf8 bx1 = *(const bf8*)(w1x1 + (size_t)(ch*16 + mp)*256 + k0 + q*8);
                bf8 aa  = *(const bf8*)&hbuf[(mt*16 + mp)*264 + k0 + q*8];
                sa = MFMA(aa & mv0, bx0, sa);
                sa = MFMA(aa & mv1, bx1, sa);
            }
        }
        __syncthreads();   // B10: all g1 reads done; alias region free

        // score epi: S shadows from regs; X^T shadow + norms by t<64
        {
            int colD = ch*16 + mp;               // 0..31 (cols >=20 exact zeros)
            #pragma unroll
            for (int r = 0; r < 4; ++r) {
                int row = mt*16 + q*4 + r, st = row >> 5, il = row & 31;
                short sb = f2bfT(sa[r]);
                SBs[row*32 + colD] = sb;
                STbS[st*1024 + colD*32 + il] = sb;
            }
        }
        if (t < 64) {
            int st = t >> 5, il = t & 31;
            float nrm = 0.f;
            #pragma unroll
            for (int d = 0; d < 20; ++d) {
                float xb = bf2f(A0s[t*96 + 64 + d]);
                nrm += xb * xb;
                XTbS[st*1024 + d*32 + il] = f2bfT(Xm[t*20 + d]);
            }
            #pragma unroll
            for (int d = 20; d < 32; ++d) XTbS[st*1024 + d*32 + il] = 0;
            normsS[t] = nrm;
        }
        __syncthreads();   // B11

        // ======== P7: Gram: d2s = n_i+n_j-2*XX^T ; GS = X S^T ========
        {
            int stw = wv >> 2, mtl = (wv >> 1) & 1, ntl = wv & 1;
            bf8 aa  = *(const bf8*)&A0s[(stw*32 + mtl*16 + mp)*96 + 64 + q*8];
            bf8 bbx = *(const bf8*)&A0s[(stw*32 + ntl*16 + mp)*96 + 64 + q*8];
            bf8 bbs = *(const bf8*)&SBs[(stw*32 + ntl*16 + mp)*32 + q*8];
            f4 gx = MFMA(aa, bbx, ((f4){0,0,0,0}));
            f4 gs = MFMA(aa, bbs, ((f4){0,0,0,0}));
            int jl = ntl*16 + mp;
            float nj = normsS[stw*32 + jl];
            #pragma unroll
            for (int r = 0; r < 4; ++r) {
                int il = mtl*16 + q*4 + r;
                d2sF[stw*1024 + il*32 + jl] = normsS[stw*32 + il] + nj - 2.f*gx[r];
                GSF [stw*1024 + il*32 + jl] = gs[r];
            }
        }
        __syncthreads();   // B12

        // ======== P8: waves 0-1 median sort (others idle) ========
        if (wv < 2) {
            const float* base = d2sF + wv*1024;
            float v[8];
            #pragma unroll
            for (int i = 0; i < 8; ++i) {
                int e = lane*8 + i;
                v[i] = (e < 496) ? base[lutI[e]*32 + lutJ[e]] : 3.4e38f;
            }
            for (int k = 2; k <= 512; k <<= 1) {
                for (int jj = k >> 1; jj >= 8; jj >>= 1) {
                    int lm = jj >> 3;
                    #pragma unroll
                    for (int i = 0; i < 8; ++i) {
                        float w = __shfl_xor(v[i], lm, 64);
                        int p = lane*8 + i;
                        bool takeMin = (((p & k) == 0) == ((p & jj) == 0));
                        v[i] = takeMin ? fminf(v[i], w) : fmaxf(v[i], w);
                    }
                }
                int jj0 = (k >> 1) < 4 ? (k >> 1) : 4;
                for (int jj = jj0; jj >= 1; jj >>= 1) {
                    #pragma unroll
                    for (int i = 0; i < 8; ++i) {
                        if ((i & jj) == 0) {
                            int i2 = i | jj;
                            int p = lane*8 + i;
                            bool up = ((p & k) == 0);
                            float x = v[i], y = v[i2];
                            float mn = fminf(x, y), mx = fmaxf(x, y);
                            v[i] = up ? mn : mx; v[i2] = up ? mx : mn;
                        }
                    }
                }
            }
            if (lane == 29) med2[wv*2 + 0] = v[7];   // sorted index 239
            if (lane == 30) med2[wv*2 + 1] = v[0];   // sorted index 240
        }
        __syncthreads();   // B13

        // ======== P9: K = exp(-g d2), logp row-terms, rowK ========
        {
            int i = t >> 3, stw = i >> 5, il = i & 31, j0 = (t & 7) * 4;
            float medv = 0.5f * (med2[stw*2] + med2[stw*2 + 1]);
            float gam  = 1.f / (2.f * (medv / (2.f * LOG33)) + 1e-8f);
            float sK = 0.f, sKGS = 0.f, sKd2 = 0.f, sKdg = 0.f;
            #pragma unroll
            for (int jj = 0; jj < 4; ++jj) {
                int j = j0 + jj;
                float d2 = d2sF[stw*1024 + il*32 + j];
                float K  = expf(-gam * d2);
                KbS[stw*1024 + il*32 + j] = f2bfT(K);
                sK   += K;
                sKGS += K * GSF[stw*1024 + il*32 + j];
                sKd2 += K * d2;
                sKdg += K * GSF[stw*1024 + j*32 + j];   // diag GS_jj = x_j·s_j
            }
            #pragma unroll
            for (int d = 1; d < 8; d <<= 1) {
                sK   += __shfl_xor(sK,   d, 64);
                sKGS += __shfl_xor(sKGS, d, 64);
                sKd2 += __shfl_xor(sKd2, d, 64);
                sKdg += __shfl_xor(sKdg, d, 64);
            }
            if ((t & 7) == 0) {
                rowKS[i] = sK;
                float sdots = sKGS - sKdg;
                float ssum  = -2.f*gam*sdots
                              - 2.f*gam*(2.f*gam*sKd2 - 20.f*(sK - 1.f));
                logps[i] -= LRC * (ssum * (1.f/32.f));
            }
        }
        __syncthreads();   // B14

        // ======== P10: phi = (K@S + 2g(x*rowK - K@X))/32 ; X += LR*phi ========
        {
            int stw = wv >> 2, mtl = (wv >> 1) & 1, ntl = wv & 1;
            float medv = 0.5f * (med2[stw*2] + med2[stw*2 + 1]);
            float gam  = 1.f / (2.f * (medv / (2.f * LOG33)) + 1e-8f);
            bf8 aa  = *(const bf8*)&KbS [stw*1024 + (mtl*16 + mp)*32 + q*8];
            bf8 b1v = *(const bf8*)&STbS[stw*1024 + (ntl*16 + mp)*32 + q*8];
            bf8 b2v = *(const bf8*)&XTbS[stw*1024 + (ntl*16 + mp)*32 + q*8];
            f4 ks = MFMA(aa, b1v, ((f4){0,0,0,0}));
            f4 kx = MFMA(aa, b2v, ((f4){0,0,0,0}));
            int dd = ntl*16 + mp;
            if (dd < 20) {
                #pragma unroll
                for (int r = 0; r < 4; ++r) {
                    int gi = stw*32 + mtl*16 + q*4 + r;
                    float xi  = Xm[gi*20 + dd];
                    float phi = (ks[r] + 2.f*gam*(xi*rowKS[gi] - kx[r])) * (1.f/32.f);
                    float nx  = xi + LRC * phi;
                    Xm[gi*20 + dd] = nx;
                    A0s[gi*96 + 64 + dd] = f2bfT(nx);
                }
            }
        }
        __syncthreads();   // B15
    } // steps

    // ================= epilogue =================
    for (int p = t; p < 64*20; p += 512) {
        int i = p / 20, d = p - i*20;
        out[(b*64 + i)*20 + d] = tanhf(Xm[p]);
    }
    if (t < 64) {
        float lt = 0.f, s0 = 0.f;
        for (int d = 0; d < 20; ++d) {
            float a  = Xm[t*20 + d];
            float x  = -2.f * a;
            float sp = fmaxf(x, 0.f) + log1pf(expf(-fabsf(x)));
            lt -= 2.f * (0.69314718056f - a - sp);
            float v = a0g[(b*64 + t)*20 + d];
            s0 += v * v;
        }
        qvS[t] = -18.3787706641f - 0.5f*s0 + logps[t] + lt;
    }
    __syncthreads();
    if (t < 2) {
        float s = 0.f;
        for (int i = 0; i < 32; ++i) s += qvS[t*32 + i];
        out[1024*32*20 + b*2 + t] = s * (1.f/32.f);
    }
}

extern "C" void kernel_launch(void* const* d_in, const int* in_sizes, int n_in,
                              void* d_out, int out_size, void* d_ws, size_t ws_size,
                              hipStream_t stream) {
    unsigned short* ws = (unsigned short*)d_ws;
    prep_weights<<<(WS_ELEMS + 255)/256, 256, 0, stream>>>(
        (const float*)d_in[2],  (const float*)d_in[4],  (const float*)d_in[6],
        (const float*)d_in[8],  (const float*)d_in[10], (const float*)d_in[12], ws);
    svgd_main<<<NBLK, 512, 0, stream>>>(
        (const float*)d_in[0],  (const float*)d_in[1],
        (const float*)d_in[3],  (const float*)d_in[5],  (const float*)d_in[7],
        (const float*)d_in[9],  (const float*)d_in[11], (const float*)d_in[13],
        (const float*)d_in[6],  (const float*)d_in[12],
        ws, (float*)d_out);
}

// Round 7
// 748.168 us; speedup vs baseline: 1.7482x; 1.1084x over previous
//
#include <hip/hip_runtime.h>
#include <math.h>

#define NPART 32
#define ADIM  20
#define ODIM  64
#define HID   256
#define NSTEPS 5
#define LRC   0.1f
#define NBLK  512     // 2 states per block
#define LOG33 3.4965075614664802f

typedef short bf8 __attribute__((ext_vector_type(8)));   // 8 bf16 (4 VGPRs)
typedef float f4  __attribute__((ext_vector_type(4)));   // MFMA C/D

// workspace layout (bf16 element offsets)
#define OW1T(n) ((n)*24576)             // [256 n][96 k]   w1^T, k-pad 84->96 (fwd L1 B)
#define OW2T(n) (49152 + (n)*65536)     // [256 n][256 k]  w2^T (fwd L2 B)
#define OW2C(n) (180224 + (n)*65536)    // raw w2 copy (bwd dh1 B)
#define OW1X(n) (311296 + (n)*8192)     // [32 d][256 n]   w1 act-rows, d>=20 zero (score B)
#define OW3B(n) (327680 + (n)*256)      // w3 bf16
#define WS_ELEMS 328192

__device__ __forceinline__ short f2bf(float x) {          // RNE f32->bf16 (prep only)
    unsigned u = __float_as_uint(x);
    u += 0x7FFFu + ((u >> 16) & 1u);
    return (short)(u >> 16);
}
__device__ __forceinline__ short f2bfT(float x) {         // truncating f32->bf16 (fast)
    return (short)(__float_as_uint(x) >> 16);
}
__device__ __forceinline__ float bf2f(short s) {
    return __uint_as_float(((unsigned)(unsigned short)s) << 16);
}

#define MFMA(a,b,c) __builtin_amdgcn_mfma_f32_16x16x32_bf16((a),(b),(c),0,0,0)

// ---------- prep: build bf16 weight images in ws ----------
__global__ void prep_weights(const float* __restrict__ w1a, const float* __restrict__ w2a,
                             const float* __restrict__ w3a, const float* __restrict__ w1b,
                             const float* __restrict__ w2b, const float* __restrict__ w3b,
                             unsigned short* __restrict__ ws)
{
    int idx = blockIdx.x * 256 + threadIdx.x;
    if (idx >= WS_ELEMS) return;
    float val;
    if (idx < 49152) {
        int net = idx / 24576, rem = idx % 24576;
        int n = rem / 96, k = rem % 96;
        const float* w1 = net ? w1b : w1a;
        val = (k < 84) ? w1[k*256 + n] : 0.f;
    } else if (idx < 180224) {
        int t2 = idx - 49152; int net = t2 / 65536, rem = t2 % 65536;
        int n = rem / 256, k = rem % 256;
        const float* w2 = net ? w2b : w2a;
        val = w2[k*256 + n];
    } else if (idx < 311296) {
        int t2 = idx - 180224; int net = t2 / 65536, rem = t2 % 65536;
        const float* w2 = net ? w2b : w2a;
        val = w2[rem];
    } else if (idx < 327680) {
        int t2 = idx - 311296; int net = t2 / 8192, rem = t2 % 8192;
        int d = rem / 256, n = rem % 256;
        const float* w1 = net ? w1b : w1a;
        val = (d < 20) ? w1[(64 + d)*256 + n] : 0.f;
    } else {
        int t2 = idx - 327680; int net = t2 / 256, k = t2 % 256;
        const float* w3 = net ? w3b : w3a;
        val = w3[k];
    }
    ws[idx] = (unsigned short)f2bf(val);
}

// ---------- main: 2 states/block, 512 threads, serial spill-proof phases ----------
// amdgpu_waves_per_eu(4,4): LDS caps us at 2 blocks/CU = 4 waves/EU anyway;
// without the max=4, the compiler targets 8 waves/EU -> 64-VGPR cap -> scratch spill
// (R3-R6 all showed phantom 50MB-700MB WRITE_SIZE from this).
__global__ void __launch_bounds__(512) __attribute__((amdgpu_waves_per_eu(4, 4)))
svgd_main(const float* __restrict__ obs,  const float* __restrict__ a0g,
          const float* __restrict__ b1a,  const float* __restrict__ b2a, const float* __restrict__ b3a,
          const float* __restrict__ b1b,  const float* __restrict__ b2b, const float* __restrict__ b3b,
          const float* __restrict__ w3af, const float* __restrict__ w3bf,
          const unsigned short* __restrict__ ws, float* __restrict__ out)
{
    __shared__ __align__(16) short A0s[64*96];      // [obs|X|pad] bf16, 2 states stacked
    __shared__ __align__(16) short hbuf[64*264];    // h1 -> g2 -> g1 bf16; RBF arrays alias
    __shared__ float Xm[64*20];                     // fp32 master particles
    __shared__ float qpart[2][8][64];
    __shared__ int   winsS[64];
    __shared__ float logps[64];
    __shared__ unsigned short lutI[496], lutJ[496];
    __shared__ float med2[4];                        // [state][2]
    __shared__ float qvS[64];
    __shared__ float normsS[64], rowKS[64];

    // hbuf alias map (short offsets) — live only in the RBF tail of each step:
    float* d2sF = (float*)hbuf;          // shorts     0.. 4095 : d2s fp32 [2][32][32]
    float* GSF  = ((float*)hbuf) + 2048; // shorts  4096.. 8191 : X@S^T fp32 (diag = x_i·s_i)
    short* KbS  = hbuf + 8192;           // shorts  8192..10239 : K bf16 [2][32][32]
    short* SBs  = hbuf + 10240;          // shorts 10240..12287 : S bf16 [64][32] (k-pad 0)
    short* STbS = hbuf + 12288;          // shorts 12288..14335 : S^T bf16 [2][32dd][32j]
    short* XTbS = hbuf + 14336;          // shorts 14336..16383 : X^T bf16 [2][32dd][32j]

    const int t = threadIdx.x, b = blockIdx.x;
    const int lane = t & 63, wv = t >> 6;           // 8 waves
    const int q = lane >> 4, mp = lane & 15;
    const int nb = wv * 32;                          // 32-col slice of the 256-wide GEMMs

    // ---- init ----
    for (int p = t; p < 64*ODIM; p += 512) {
        int i = p >> 6, d = p & 63;
        A0s[i*96 + d] = f2bfT(obs[(b*64 + i)*ODIM + d]);
    }
    for (int p = t; p < 64*ADIM; p += 512) {
        int i = p / 20, d = p - i*20;
        float v = a0g[(b*64 + i)*20 + d];
        Xm[p] = v;
        A0s[i*96 + 64 + d] = f2bfT(v);
    }
    for (int p = t; p < 64*12; p += 512) { int i = p/12, d = p - i*12; A0s[i*96 + 84 + d] = 0; }
    if (t < 496) {
        int i_ = 0, rem = t;
        while (rem >= 31 - i_) { rem -= 31 - i_; ++i_; }
        lutI[t] = (unsigned short)i_; lutJ[t] = (unsigned short)(i_ + 1 + rem);
    }
    if (t < 64) logps[t] = 0.f;
    __syncthreads();

    const int mt = wv & 3, ch = wv >> 2;             // score tile mapping

    for (int step = 0; step < NSTEPS; ++step) {
        f4 sav[2];                                    // per-net ungated score frags

        for (int net = 0; net < 2; ++net) {
            const unsigned short* w1t = ws + OW1T(net);
            const unsigned short* w2t = ws + OW2T(net);
            const unsigned short* w2c = ws + OW2C(net);
            const unsigned short* w1x = ws + OW1X(net);
            const float* b1p = net ? b1b : b1a;
            const float* b2p = net ? b2b : b2a;
            const float* w3p = net ? w3bf : w3af;
            unsigned m0reg;                           // relu-L1 bits (h*8+s*4+r)

            // ---- fwd L1: [64x96] @ w1t -> h1 ----
            {
                f4 acc[4][2];
                #pragma unroll
                for (int h = 0; h < 4; ++h) { acc[h][0] = (f4){0,0,0,0}; acc[h][1] = (f4){0,0,0,0}; }
                #pragma unroll
                for (int k0 = 0; k0 < 96; k0 += 32) {
                    bf8 bb0 = *(const bf8*)(w1t + (size_t)(nb +      mp)*96 + k0 + q*8);
                    bf8 bb1 = *(const bf8*)(w1t + (size_t)(nb + 16 + mp)*96 + k0 + q*8);
                    #pragma unroll
                    for (int h = 0; h < 4; ++h) {
                        bf8 aa = *(const bf8*)&A0s[(h*16 + mp)*96 + k0 + q*8];
                        acc[h][0] = MFMA(aa, bb0, acc[h][0]);
                        acc[h][1] = MFMA(aa, bb1, acc[h][1]);
                    }
                }
                unsigned mbits = 0u;
                #pragma unroll
                for (int h = 0; h < 4; ++h) {
                    #pragma unroll
                    for (int s = 0; s < 2; ++s) {
                        int col = nb + s*16 + mp;
                        float bias = b1p[col];
                        #pragma unroll
                        for (int r = 0; r < 4; ++r) {
                            float v = acc[h][s][r] + bias;
                            bool pos = v > 0.f;
                            if (pos) mbits |= 1u << (h*8 + s*4 + r);
                            hbuf[(h*16 + q*4 + r)*264 + col] = f2bfT(pos ? v : 0.f);
                        }
                    }
                }
                m0reg = mbits;
            }
            __syncthreads();                          // h1 ready

            // ---- fwd L2: h1 @ w2t ; epi: qpart, posreg; then g2 -> hbuf ----
            {
                f4 acc[4][2];
                #pragma unroll
                for (int h = 0; h < 4; ++h) { acc[h][0] = (f4){0,0,0,0}; acc[h][1] = (f4){0,0,0,0}; }
                #pragma unroll
                for (int k0 = 0; k0 < 256; k0 += 32) {
                    bf8 bb0 = *(const bf8*)(w2t + (size_t)(nb +      mp)*256 + k0 + q*8);
                    bf8 bb1 = *(const bf8*)(w2t + (size_t)(nb + 16 + mp)*256 + k0 + q*8);
                    #pragma unroll
                    for (int h = 0; h < 4; ++h) {
                        bf8 aa = *(const bf8*)&hbuf[(h*16 + mp)*264 + k0 + q*8];
                        acc[h][0] = MFMA(aa, bb0, acc[h][0]);
                        acc[h][1] = MFMA(aa, bb1, acc[h][1]);
                    }
                }
                unsigned posreg = 0u;
                {
                    float qp[4][4] = {{0,0,0,0},{0,0,0,0},{0,0,0,0},{0,0,0,0}};
                    #pragma unroll
                    for (int h = 0; h < 4; ++h) {
                        #pragma unroll
                        for (int s = 0; s < 2; ++s) {
                            int col = nb + s*16 + mp;
                            float bias = b2p[col], w3v = w3p[col];
                            #pragma unroll
                            for (int r = 0; r < 4; ++r) {
                                float v = acc[h][s][r] + bias;
                                bool pos = v > 0.f;
                                if (pos) posreg |= 1u << (h*8 + s*4 + r);
                                qp[h][r] += pos ? v * w3v : 0.f;
                            }
                        }
                    }
                    #pragma unroll
                    for (int d = 1; d < 16; d <<= 1)
                        #pragma unroll
                        for (int h = 0; h < 4; ++h)
                            #pragma unroll
                            for (int r = 0; r < 4; ++r)
                                qp[h][r] += __shfl_xor(qp[h][r], d, 64);
                    if (mp == 0) {
                        #pragma unroll
                        for (int h = 0; h < 4; ++h)
                            #pragma unroll
                            for (int r = 0; r < 4; ++r)
                                qpart[net][wv][h*16 + q*4 + r] = qp[h][r];
                    }
                }
                __syncthreads();                      // h1 reads + qpart done
                // g2 = relu'(z2)*w3 (bf16) -> hbuf
                short w3s0 = (short)ws[OW3B(net) + nb + mp];
                short w3s1 = (short)ws[OW3B(net) + nb + 16 + mp];
                #pragma unroll
                for (int h = 0; h < 4; ++h) {
                    #pragma unroll
                    for (int s = 0; s < 2; ++s) {
                        int col = nb + s*16 + mp;
                        short wv3 = s ? w3s1 : w3s0;
                        #pragma unroll
                        for (int r = 0; r < 4; ++r) {
                            bool on = (posreg >> (h*8 + s*4 + r)) & 1u;
                            hbuf[(h*16 + q*4 + r)*264 + col] = on ? wv3 : (short)0;
                        }
                    }
                }
                if (net == 1 && t < 64) {             // argmin (qpart[0],[1] both ready)
                    float q0 = b3a[0], q1 = b3b[0];
                    #pragma unroll
                    for (int w = 0; w < 8; ++w) { q0 += qpart[0][w][t]; q1 += qpart[1][w][t]; }
                    winsS[t] = (q0 <= q1) ? 0 : 1;
                }
            }
            __syncthreads();                          // g2 (+ winsS) ready

            // ---- bwd dh1: g2 @ w2c (std GEMM); write g1 = dh1 * mask0 ----
            {
                f4 accB[4][2];
                #pragma unroll
                for (int h = 0; h < 4; ++h) { accB[h][0] = (f4){0,0,0,0}; accB[h][1] = (f4){0,0,0,0}; }
                #pragma unroll
                for (int k0 = 0; k0 < 256; k0 += 32) {
                    bf8 c0 = *(const bf8*)(w2c + (size_t)(nb +      mp)*256 + k0 + q*8);
                    bf8 c1 = *(const bf8*)(w2c + (size_t)(nb + 16 + mp)*256 + k0 + q*8);
                    #pragma unroll
                    for (int h = 0; h < 4; ++h) {
                        bf8 aa = *(const bf8*)&hbuf[(h*16 + mp)*264 + k0 + q*8];
                        accB[h][0] = MFMA(aa, c0, accB[h][0]);
                        accB[h][1] = MFMA(aa, c1, accB[h][1]);
                    }
                }
                __syncthreads();                      // g2 reads done
                #pragma unroll
                for (int h = 0; h < 4; ++h) {
                    #pragma unroll
                    for (int s = 0; s < 2; ++s) {
                        int col = nb + s*16 + mp;
                        #pragma unroll
                        for (int r = 0; r < 4; ++r) {
                            bool on = (m0reg >> (h*8 + s*4 + r)) & 1u;
                            hbuf[(h*16 + q*4 + r)*264 + col] = f2bfT(on ? accB[h][s][r] : 0.f);
                        }
                    }
                }
            }
            __syncthreads();                          // g1 ready

            // ---- score (ungated rows): g1 @ w1x -> sav[net] ----
            {
                f4 sa = (f4){0,0,0,0};
                #pragma unroll
                for (int k0 = 0; k0 < 256; k0 += 32) {
                    bf8 bx = *(const bf8*)(w1x + (size_t)(ch*16 + mp)*256 + k0 + q*8);
                    bf8 aa = *(const bf8*)&hbuf[(mt*16 + mp)*264 + k0 + q*8];
                    sa = MFMA(aa, bx, sa);
                }
                sav[net] = sa;
            }
            __syncthreads();                          // g1 reads done
        } // net

        // ---- row-gated score select + S shadows; XT + norms ----
        {
            int colD = ch*16 + mp;               // 0..31 (cols >=20 exact zeros)
            #pragma unroll
            for (int r = 0; r < 4; ++r) {
                int row = mt*16 + q*4 + r, st = row >> 5, il = row & 31;
                float sv = winsS[row] ? sav[1][r] : sav[0][r];
                short sb = f2bfT(sv);
                SBs[row*32 + colD] = sb;
                STbS[st*1024 + colD*32 + il] = sb;
            }
        }
        if (t < 64) {
            int st = t >> 5, il = t & 31;
            float nrm = 0.f;
            #pragma unroll
            for (int d = 0; d < 20; ++d) {
                float xb = bf2f(A0s[t*96 + 64 + d]);
                nrm += xb * xb;
                XTbS[st*1024 + d*32 + il] = f2bfT(Xm[t*20 + d]);
            }
            #pragma unroll
            for (int d = 20; d < 32; ++d) XTbS[st*1024 + d*32 + il] = 0;
            normsS[t] = nrm;
        }
        __syncthreads();

        // ---- Gram: d2s = n_i+n_j-2*XX^T ; GS = X S^T ----
        {
            int stw = wv >> 2, mtl = (wv >> 1) & 1, ntl = wv & 1;
            bf8 aa  = *(const bf8*)&A0s[(stw*32 + mtl*16 + mp)*96 + 64 + q*8];
            bf8 bbx = *(const bf8*)&A0s[(stw*32 + ntl*16 + mp)*96 + 64 + q*8];
            bf8 bbs = *(const bf8*)&SBs[(stw*32 + ntl*16 + mp)*32 + q*8];
            f4 gx = MFMA(aa, bbx, ((f4){0,0,0,0}));
            f4 gs = MFMA(aa, bbs, ((f4){0,0,0,0}));
            int jl = ntl*16 + mp;
            float nj = normsS[stw*32 + jl];
            #pragma unroll
            for (int r = 0; r < 4; ++r) {
                int il = mtl*16 + q*4 + r;
                d2sF[stw*1024 + il*32 + jl] = normsS[stw*32 + il] + nj - 2.f*gx[r];
                GSF [stw*1024 + il*32 + jl] = gs[r];
            }
        }
        __syncthreads();

        // ---- median sort (waves 0-1, in-register bitonic) ----
        if (wv < 2) {
            const float* base = d2sF + wv*1024;
            float v[8];
            #pragma unroll
            for (int i = 0; i < 8; ++i) {
                int e = lane*8 + i;
                v[i] = (e < 496) ? base[lutI[e]*32 + lutJ[e]] : 3.4e38f;
            }
            for (int k = 2; k <= 512; k <<= 1) {
                for (int jj = k >> 1; jj >= 8; jj >>= 1) {
                    int lm = jj >> 3;
                    #pragma unroll
                    for (int i = 0; i < 8; ++i) {
                        float w = __shfl_xor(v[i], lm, 64);
                        int p = lane*8 + i;
                        bool takeMin = (((p & k) == 0) == ((p & jj) == 0));
                        v[i] = takeMin ? fminf(v[i], w) : fmaxf(v[i], w);
                    }
                }
                int jj0 = (k >> 1) < 4 ? (k >> 1) : 4;
                for (int jj = jj0; jj >= 1; jj >>= 1) {
                    #pragma unroll
                    for (int i = 0; i < 8; ++i) {
                        if ((i & jj) == 0) {
                            int i2 = i | jj;
                            int p = lane*8 + i;
                            bool up = ((p & k) == 0);
                            float x = v[i], y = v[i2];
                            float mn = fminf(x, y), mx = fmaxf(x, y);
                            v[i] = up ? mn : mx; v[i2] = up ? mx : mn;
                        }
                    }
                }
            }
            if (lane == 29) med2[wv*2 + 0] = v[7];   // sorted index 239
            if (lane == 30) med2[wv*2 + 1] = v[0];   // sorted index 240
        }
        __syncthreads();

        // ---- K = exp(-g d2), logp row-terms, rowK ----
        {
            int i = t >> 3, stw = i >> 5, il = i & 31, j0 = (t & 7) * 4;
            float medv = 0.5f * (med2[stw*2] + med2[stw*2 + 1]);
            float gam  = 1.f / (2.f * (medv / (2.f * LOG33)) + 1e-8f);
            float sK = 0.f, sKGS = 0.f, sKd2 = 0.f, sKdg = 0.f;
            #pragma unroll
            for (int jj = 0; jj < 4; ++jj) {
                int j = j0 + jj;
                float d2 = d2sF[stw*1024 + il*32 + j];
                float K  = expf(-gam * d2);
                KbS[stw*1024 + il*32 + j] = f2bfT(K);
                sK   += K;
                sKGS += K * GSF[stw*1024 + il*32 + j];
                sKd2 += K * d2;
                sKdg += K * GSF[stw*1024 + j*32 + j];   // diag GS_jj = x_j·s_j
            }
            #pragma unroll
            for (int d = 1; d < 8; d <<= 1) {
                sK   += __shfl_xor(sK,   d, 64);
                sKGS += __shfl_xor(sKGS, d, 64);
                sKd2 += __shfl_xor(sKd2, d, 64);
                sKdg += __shfl_xor(sKdg, d, 64);
            }
            if ((t & 7) == 0) {
                rowKS[i] = sK;
                float sdots = sKGS - sKdg;
                float ssum  = -2.f*gam*sdots
                              - 2.f*gam*(2.f*gam*sKd2 - 20.f*(sK - 1.f));
                logps[i] -= LRC * (ssum * (1.f/32.f));
            }
        }
        __syncthreads();

        // ---- phi = (K@S + 2g(x*rowK - K@X))/32 ; X += LR*phi ----
        {
            int stw = wv >> 2, mtl = (wv >> 1) & 1, ntl = wv & 1;
            float medv = 0.5f * (med2[stw*2] + med2[stw*2 + 1]);
            float gam  = 1.f / (2.f * (medv / (2.f * LOG33)) + 1e-8f);
            bf8 aa  = *(const bf8*)&KbS [stw*1024 + (mtl*16 + mp)*32 + q*8];
            bf8 b1v = *(const bf8*)&STbS[stw*1024 + (ntl*16 + mp)*32 + q*8];
            bf8 b2v = *(const bf8*)&XTbS[stw*1024 + (ntl*16 + mp)*32 + q*8];
            f4 ks = MFMA(aa, b1v, ((f4){0,0,0,0}));
            f4 kx = MFMA(aa, b2v, ((f4){0,0,0,0}));
            int dd = ntl*16 + mp;
            if (dd < 20) {
                #pragma unroll
                for (int r = 0; r < 4; ++r) {
                    int gi = stw*32 + mtl*16 + q*4 + r;
                    float xi  = Xm[gi*20 + dd];
                    float phi = (ks[r] + 2.f*gam*(xi*rowKS[gi] - kx[r])) * (1.f/32.f);
                    float nx  = xi + LRC * phi;
                    Xm[gi*20 + dd] = nx;
                    A0s[gi*96 + 64 + dd] = f2bfT(nx);
                }
            }
        }
        __syncthreads();
    } // steps

    // ================= epilogue =================
    for (int p = t; p < 64*20; p += 512) {
        int i = p / 20, d = p - i*20;
        out[(b*64 + i)*20 + d] = tanhf(Xm[p]);
    }
    if (t < 64) {
        float lt = 0.f, s0 = 0.f;
        for (int d = 0; d < 20; ++d) {
            float a  = Xm[t*20 + d];
            float x  = -2.f * a;
            float sp = fmaxf(x, 0.f) + log1pf(expf(-fabsf(x)));
            lt -= 2.f * (0.69314718056f - a - sp);
            float v = a0g[(b*64 + t)*20 + d];
            s0 += v * v;
        }
        qvS[t] = -18.3787706641f - 0.5f*s0 + logps[t] + lt;
    }
    __syncthreads();
    if (t < 2) {
        float s = 0.f;
        for (int i = 0; i < 32; ++i) s += qvS[t*32 + i];
        out[1024*32*20 + b*2 + t] = s * (1.f/32.f);
    }
}

extern "C" void kernel_launch(void* const* d_in, const int* in_sizes, int n_in,
                              void* d_out, int out_size, void* d_ws, size_t ws_size,
                              hipStream_t stream) {
    unsigned short* ws = (unsigned short*)d_ws;
    prep_weights<<<(WS_ELEMS + 255)/256, 256, 0, stream>>>(
        (const float*)d_in[2],  (const float*)d_in[4],  (const float*)d_in[6],
        (const float*)d_in[8],  (const float*)d_in[10], (const float*)d_in[12], ws);
    svgd_main<<<NBLK, 512, 0, stream>>>(
        (const float*)d_in[0],  (const float*)d_in[1],
        (const float*)d_in[3],  (const float*)d_in[5],  (const float*)d_in[7],
        (const float*)d_in[9],  (const float*)d_in[11], (const float*)d_in[13],
        (const float*)d_in[6],  (const float*)d_in[12],
        ws, (float*)d_out);
}